// Round 6
// baseline (228.313 us; speedup 1.0000x reference)
//
#include <hip/hip_runtime.h>
#include <hip/hip_bf16.h>
#include <math.h>

// Problem constants (fixed by setup_inputs)
#define BB   256
#define DIN  2048
#define DD   512
#define CC   1000
#define NN   50000
#define MM   (NN + BB)     // 50256
#define FILTER_K 100
#define SLOT 512           // per-class capacity; max real ~90 old + <=256 new

#define SK1  32            // split-K for z = x@Wf  (klen 64)
#define SKP  8             // split-K for p = z@Wc^T (klen 64)

// ---------------- workspace layout (float elements) ----------------
#define Z_OFF     0                          // z:     [256][512]
#define CNT_OFF   (Z_OFF + BB*DD)            // cnt:   [1024] int
#define ENTS_OFF  (CNT_OFF + 1024)           // ent_s: [1000][512]
#define IDXS_OFF  (ENTS_OFF + CC*SLOT)       // idx_s: [1000][512] int
#define WN_OFF    (IDXS_OFF + CC*SLOT)       // wn:    [1000][512]
#define ZP_OFF    (WN_OFF + CC*DD)           // zpart: [32][256][512]
#define PP_OFF    (ZP_OFF + SK1*BB*DD)       // ppart: [8][256][1000]
// total ~7.3M floats ~29 MB (< 400 MB ws)

// ==== Node 2 (fused): blocks 0..511 -> zpart = x@Wf slice; ====
// ==== blocks 512..707 -> old-row scatter into class slots.  ====
// GEMM: 64x128 tile, 4x8 micro, BK=16, klen=64.
__global__ __launch_bounds__(256, 2) void fused_scatter_gemm_ab(
    const float* __restrict__ A, const float* __restrict__ B,
    float* __restrict__ Cp,
    const int* __restrict__ labels_idx, const float* __restrict__ ent_in,
    int* __restrict__ cnt, float* __restrict__ ent_s,
    int* __restrict__ idx_s) {
  __shared__ float As[16][68];
  __shared__ float Bs[16][132];
  const int gbid = blockIdx.x, tid = threadIdx.x;
  if (gbid >= 512) {   // ---- scatter branch ----
    int m = (gbid - 512) * 256 + tid;
    if (m < NN) {
      int c = labels_idx[m];
      int pos = atomicAdd(&cnt[c], 1);
      if (pos < SLOT) {
        ent_s[(size_t)c * SLOT + pos] = ent_in[m];
        idx_s[(size_t)c * SLOT + pos] = m;
      }
    }
    return;
  }
  // ---- GEMM branch ----
  const int m0 = ((gbid >> 2) & 3) * 64;
  const int n0 = (gbid & 3) * 128;
  const int k0 = (gbid >> 4) * 64;
  const int ar = tid >> 2, ac = (tid & 3) * 4;   // A: 64 rows x 16 k
  const int br = tid >> 4, bcn = (tid & 15) * 8; // B: 16 k x 128 n
  const int tm = (tid >> 4) * 4, tn = (tid & 15) * 4;
  float acc[4][8] = {};
  float4 av  = *(const float4*)&A[(size_t)(m0 + ar) * DIN + k0 + ac];
  float4 bv0 = *(const float4*)&B[(size_t)(k0 + br) * DD + n0 + bcn];
  float4 bv1 = *(const float4*)&B[(size_t)(k0 + br) * DD + n0 + bcn + 4];
  for (int kk = 0; kk < 64; kk += 16) {
    __syncthreads();
    As[ac + 0][ar] = av.x; As[ac + 1][ar] = av.y;
    As[ac + 2][ar] = av.z; As[ac + 3][ar] = av.w;
    *(float4*)&Bs[br][bcn] = bv0;
    *(float4*)&Bs[br][bcn + 4] = bv1;
    __syncthreads();
    if (kk + 16 < 64) {   // register prefetch of next K-tile
      av  = *(const float4*)&A[(size_t)(m0 + ar) * DIN + k0 + kk + 16 + ac];
      bv0 = *(const float4*)&B[(size_t)(k0 + kk + 16 + br) * DD + n0 + bcn];
      bv1 = *(const float4*)&B[(size_t)(k0 + kk + 16 + br) * DD + n0 + bcn + 4];
    }
#pragma unroll
    for (int q = 0; q < 16; ++q) {
      float4 a  = *(const float4*)&As[q][tm];
      float4 b0 = *(const float4*)&Bs[q][tn];
      float4 b1 = *(const float4*)&Bs[q][tn + 64];
      float aa[4] = {a.x, a.y, a.z, a.w};
      float bb[8] = {b0.x, b0.y, b0.z, b0.w, b1.x, b1.y, b1.z, b1.w};
#pragma unroll
      for (int i = 0; i < 4; ++i)
#pragma unroll
        for (int j = 0; j < 8; ++j) acc[i][j] += aa[i] * bb[j];
    }
  }
  float* Cb = Cp + (size_t)(gbid >> 4) * BB * DD;
#pragma unroll
  for (int i = 0; i < 4; ++i) {
    *(float4*)&Cb[(size_t)(m0 + tm + i) * DD + n0 + tn] =
        make_float4(acc[i][0], acc[i][1], acc[i][2], acc[i][3]);
    *(float4*)&Cb[(size_t)(m0 + tm + i) * DD + n0 + 64 + tn] =
        make_float4(acc[i][4], acc[i][5], acc[i][6], acc[i][7]);
  }
}

// ============ Node 3: z = sum of 32 split-K partials ================
template <int S>
__global__ __launch_bounds__(256) void reduce_part(
    const float* __restrict__ part, float* __restrict__ out, int n4) {
  int i = blockIdx.x * 256 + threadIdx.x;
  if (i >= n4) return;
  const float4* p4 = (const float4*)part;
  float4 a = p4[i];
#pragma unroll
  for (int s = 1; s < S; ++s) {
    float4 b = p4[(size_t)s * n4 + i];
    a.x += b.x; a.y += b.y; a.z += b.z; a.w += b.w;
  }
  ((float4*)out)[i] = a;
}

// ==== Node 4: ppart[s] = z @ Wc^T  64x64 tile, 4x4 micro, klen=64 ====
__global__ __launch_bounds__(256, 2) void gemm_abt_part(
    const float* __restrict__ A, const float* __restrict__ Bm,
    float* __restrict__ Cp) {
  __shared__ float As[16][68];
  __shared__ float Bs[16][68];
  const int tid = threadIdx.x;
  const int m0 = blockIdx.y * 64;
  const int n0 = blockIdx.x * 64;
  const int k0 = blockIdx.z * 64;
  const int ar = tid >> 2, ac = (tid & 3) * 4;   // 64 rows x 16 k
  const int tm = (tid >> 4) * 4, tn = (tid & 15) * 4;
  float acc[4][4] = {};
  float4 av = *(const float4*)&A[(size_t)(m0 + ar) * DD + k0 + ac];
  float4 bv = make_float4(0.f, 0.f, 0.f, 0.f);
  if (n0 + ar < CC) bv = *(const float4*)&Bm[(size_t)(n0 + ar) * DD + k0 + ac];
  for (int kk = 0; kk < 64; kk += 16) {
    __syncthreads();
    As[ac + 0][ar] = av.x; As[ac + 1][ar] = av.y;
    As[ac + 2][ar] = av.z; As[ac + 3][ar] = av.w;
    Bs[ac + 0][ar] = bv.x; Bs[ac + 1][ar] = bv.y;
    Bs[ac + 2][ar] = bv.z; Bs[ac + 3][ar] = bv.w;
    __syncthreads();
    if (kk + 16 < 64) {   // register prefetch
      av = *(const float4*)&A[(size_t)(m0 + ar) * DD + k0 + kk + 16 + ac];
      if (n0 + ar < CC)
        bv = *(const float4*)&Bm[(size_t)(n0 + ar) * DD + k0 + kk + 16 + ac];
    }
#pragma unroll
    for (int q = 0; q < 16; ++q) {
      float4 a = *(const float4*)&As[q][tm];
      float4 b = *(const float4*)&Bs[q][tn];
      float aa[4] = {a.x, a.y, a.z, a.w};
      float bb[4] = {b.x, b.y, b.z, b.w};
#pragma unroll
      for (int i = 0; i < 4; ++i)
#pragma unroll
        for (int j = 0; j < 4; ++j) acc[i][j] += aa[i] * bb[j];
    }
  }
  float* Cb = Cp + (size_t)blockIdx.z * BB * CC;
#pragma unroll
  for (int i = 0; i < 4; ++i) {
    int n = n0 + tn;
    if (n + 3 < CC) {
      *(float4*)&Cb[(size_t)(m0 + tm + i) * CC + n] =
          make_float4(acc[i][0], acc[i][1], acc[i][2], acc[i][3]);
    } else {
#pragma unroll
      for (int j = 0; j < 4; ++j)
        if (n + j < CC) Cb[(size_t)(m0 + tm + i) * CC + n + j] = acc[i][j];
    }
  }
}

// == Node 5: per-row argmax + entropy over p-partials + bias; scatters NEW row ==
__global__ __launch_bounds__(256) void rowstats(
    const float* __restrict__ ppart, const float* __restrict__ bc,
    int* __restrict__ cnt, float* __restrict__ ent_s,
    int* __restrict__ idx_s) {
  const int b = blockIdx.x, tid = threadIdx.x;
  const int lane = tid & 63, wid = tid >> 6;
  float r[4];
  float mv = -INFINITY; int mi = 0x7fffffff;
#pragma unroll
  for (int i = 0; i < 4; ++i) {
    int c = tid + 256 * i;
    if (c < CC) {
      float v = bc[c];
#pragma unroll
      for (int s = 0; s < SKP; ++s)
        v += ppart[(size_t)s * BB * CC + (size_t)b * CC + c];
      r[i] = v;
    } else r[i] = -INFINITY;
    if (r[i] > mv) { mv = r[i]; mi = c; }   // ascending c keeps first max
  }
#pragma unroll
  for (int o = 32; o > 0; o >>= 1) {
    float ov = __shfl_down(mv, o, 64);
    int oi = __shfl_down(mi, o, 64);
    if (ov > mv || (ov == mv && oi < mi)) { mv = ov; mi = oi; }
  }
  __shared__ float smv[4]; __shared__ int smi[4];
  __shared__ float ssm[4], tsm[4];
  if (lane == 0) { smv[wid] = mv; smi[wid] = mi; }
  __syncthreads();
  if (tid == 0) {
#pragma unroll
    for (int w = 1; w < 4; ++w)
      if (smv[w] > smv[0] || (smv[w] == smv[0] && smi[w] < smi[0])) {
        smv[0] = smv[w]; smi[0] = smi[w];
      }
  }
  __syncthreads();
  const float m = smv[0]; const int am = smi[0];
  float s = 0.f, t = 0.f;
#pragma unroll
  for (int i = 0; i < 4; ++i) {
    if (tid + 256 * i < CC) {
      float u = r[i] - m;
      float e = expf(u);
      s += e; t += u * e;
    }
  }
#pragma unroll
  for (int o = 32; o > 0; o >>= 1) {
    s += __shfl_down(s, o, 64);
    t += __shfl_down(t, o, 64);
  }
  if (lane == 0) { ssm[wid] = s; tsm[wid] = t; }
  __syncthreads();
  if (tid == 0) {   // scatter this block's NEW row (original index NN+b)
    float S = ssm[0] + ssm[1] + ssm[2] + ssm[3];
    float T = tsm[0] + tsm[1] + tsm[2] + tsm[3];
    float ent = logf(S) - T / S;
    int pos = atomicAdd(&cnt[am], 1);
    if (pos < SLOT) {
      ent_s[(size_t)am * SLOT + pos] = ent;
      idx_s[(size_t)am * SLOT + pos] = NN + b;
    }
  }
}

// == Node 6: per-class select-K, sum normalized rows, column norm ==
// ILP-4 streaming: 4 rows in flight per wave, 4 interleaved shfl chains.
__global__ __launch_bounds__(256) void class_weights(
    const float* __restrict__ supports_in, const float* __restrict__ z,
    const float* __restrict__ ent_s, const int* __restrict__ idx_s,
    const int* __restrict__ cnt, float* __restrict__ wn) {
  const int c = blockIdx.x, tid = threadIdx.x;
  const int lane = tid & 63, wid = tid >> 6;
  int n = cnt[c]; if (n > SLOT) n = SLOT;

  __shared__ int sel[SLOT];
  __shared__ float se[SLOT];
  __shared__ int si[SLOT];
  int seln;
  if (n <= FILTER_K) {
    seln = n;
    for (int i = tid; i < n; i += 256) sel[i] = idx_s[(size_t)c * SLOT + i];
  } else {
    for (int i = tid; i < SLOT; i += 256) {
      if (i < n) { se[i] = ent_s[(size_t)c * SLOT + i]; si[i] = idx_s[(size_t)c * SLOT + i]; }
      else       { se[i] = INFINITY;                     si[i] = 0x7fffffff; }
    }
    __syncthreads();
    for (int k = 2; k <= SLOT; k <<= 1)
      for (int j = k >> 1; j > 0; j >>= 1) {
        for (int i = tid; i < SLOT; i += 256) {
          int ixj = i ^ j;
          if (ixj > i) {
            bool up = ((i & k) == 0);
            float e1 = se[i], e2 = se[ixj];
            int i1 = si[i], i2 = si[ixj];
            bool gt = (e1 > e2) || (e1 == e2 && i1 > i2);
            if (gt == up) { se[i] = e2; se[ixj] = e1; si[i] = i2; si[ixj] = i1; }
          }
        }
        __syncthreads();
      }
    seln = FILTER_K;
    for (int i = tid; i < FILTER_K; i += 256) sel[i] = si[i];
  }
  __syncthreads();
  // pad sel to a multiple of 16 with a valid index; padded rows get scale 0
  const int seln_pad = (seln + 15) & ~15;
  if (seln > 0)
    for (int i = seln + tid; i < seln_pad; i += 256) sel[i] = sel[0];
  __syncthreads();

  // lane owns dims [lane*8, lane*8+8); wave handles 4 rows per iteration
  float4 a0 = make_float4(0.f, 0.f, 0.f, 0.f), a1 = a0;
  for (int t = wid * 4; t < seln_pad; t += 16) {
    float4 u0[4], u1[4]; float s[4];
#pragma unroll
    for (int j = 0; j < 4; ++j) {
      int r = sel[t + j];
      const float4* p4 = (const float4*)((r < NN)
          ? supports_in + (size_t)r * DD : z + (size_t)(r - NN) * DD);
      u0[j] = p4[lane * 2]; u1[j] = p4[lane * 2 + 1];
    }
#pragma unroll
    for (int j = 0; j < 4; ++j)
      s[j] = u0[j].x * u0[j].x + u0[j].y * u0[j].y + u0[j].z * u0[j].z
           + u0[j].w * u0[j].w + u1[j].x * u1[j].x + u1[j].y * u1[j].y
           + u1[j].z * u1[j].z + u1[j].w * u1[j].w;
#pragma unroll
    for (int o = 1; o < 64; o <<= 1) {
#pragma unroll
      for (int j = 0; j < 4; ++j) s[j] += __shfl_xor(s[j], o, 64);
    }
#pragma unroll
    for (int j = 0; j < 4; ++j) {
      float sc = (t + j < seln) ? 1.0f / fmaxf(sqrtf(s[j]), 1e-12f) : 0.f;
      a0.x += u0[j].x * sc; a0.y += u0[j].y * sc;
      a0.z += u0[j].z * sc; a0.w += u0[j].w * sc;
      a1.x += u1[j].x * sc; a1.y += u1[j].y * sc;
      a1.z += u1[j].z * sc; a1.w += u1[j].w * sc;
    }
  }

  __shared__ float part[4][DD];
  *(float4*)&part[wid][lane * 8] = a0;
  *(float4*)&part[wid][lane * 8 + 4] = a1;
  __syncthreads();
  const int d = tid * 2;
  float wx = part[0][d] + part[1][d] + part[2][d] + part[3][d];
  float wy = part[0][d + 1] + part[1][d + 1] + part[2][d + 1] + part[3][d + 1];
  float ss = wx * wx + wy * wy;
#pragma unroll
  for (int o = 1; o < 64; o <<= 1) ss += __shfl_xor(ss, o, 64);
  __shared__ float tot[4];
  if (lane == 0) tot[wid] = ss;
  __syncthreads();
  float S = tot[0] + tot[1] + tot[2] + tot[3];
  float sc = 1.0f / fmaxf(sqrtf(S), 1e-12f);
  ((float2*)(wn + (size_t)c * DD))[tid] = make_float2(wx * sc, wy * sc);
}

// ==== Node 7: out = z @ wn^T, full K=512, 32x64 tile, 2x4 micro ====
__global__ __launch_bounds__(256, 2) void gemm_out(
    const float* __restrict__ A, const float* __restrict__ Bm,
    float* __restrict__ C) {
  __shared__ float As[16][36];
  __shared__ float Bs[16][68];
  const int tid = threadIdx.x;
  const int m0 = blockIdx.y * 32;
  const int n0 = blockIdx.x * 64;
  const int ar = tid >> 3, ac = (tid & 7) * 2;   // A: 32 rows x 16 k (float2)
  const int br = tid >> 2, bc = (tid & 3) * 4;   // B: 64 rows x 16 k (float4)
  const int tm = (tid >> 4) * 2, tn = (tid & 15) * 4;
  float acc[2][4] = {};
  float2 av = *(const float2*)&A[(size_t)(m0 + ar) * DD + ac];
  float4 bv = make_float4(0.f, 0.f, 0.f, 0.f);
  if (n0 + br < CC) bv = *(const float4*)&Bm[(size_t)(n0 + br) * DD + bc];
  for (int k0 = 0; k0 < DD; k0 += 16) {
    __syncthreads();
    As[ac + 0][ar] = av.x; As[ac + 1][ar] = av.y;
    Bs[bc + 0][br] = bv.x; Bs[bc + 1][br] = bv.y;
    Bs[bc + 2][br] = bv.z; Bs[bc + 3][br] = bv.w;
    __syncthreads();
    if (k0 + 16 < DD) {   // register prefetch
      av = *(const float2*)&A[(size_t)(m0 + ar) * DD + k0 + 16 + ac];
      if (n0 + br < CC)
        bv = *(const float4*)&Bm[(size_t)(n0 + br) * DD + k0 + 16 + bc];
    }
#pragma unroll
    for (int q = 0; q < 16; ++q) {
      float2 a = *(const float2*)&As[q][tm];
      float4 b = *(const float4*)&Bs[q][tn];
      float aa[2] = {a.x, a.y};
      float bb[4] = {b.x, b.y, b.z, b.w};
#pragma unroll
      for (int i = 0; i < 2; ++i)
#pragma unroll
        for (int j = 0; j < 4; ++j) acc[i][j] += aa[i] * bb[j];
    }
  }
#pragma unroll
  for (int i = 0; i < 2; ++i) {
    int n = n0 + tn;
    if (n + 3 < CC) {
      *(float4*)&C[(size_t)(m0 + tm + i) * CC + n] =
          make_float4(acc[i][0], acc[i][1], acc[i][2], acc[i][3]);
    } else {
#pragma unroll
      for (int j = 0; j < 4; ++j)
        if (n + j < CC) C[(size_t)(m0 + tm + i) * CC + n + j] = acc[i][j];
    }
  }
}

// ============================ launcher ===================================
extern "C" void kernel_launch(void* const* d_in, const int* in_sizes, int n_in,
                              void* d_out, int out_size, void* d_ws, size_t ws_size,
                              hipStream_t stream) {
  (void)in_sizes; (void)n_in; (void)out_size; (void)ws_size;
  const float* x           = (const float*)d_in[0];
  const float* Wf          = (const float*)d_in[1];
  const float* Wc          = (const float*)d_in[2];
  const float* bc          = (const float*)d_in[3];
  const float* supports_in = (const float*)d_in[4];
  const float* ent_in      = (const float*)d_in[5];
  const int*   labels_idx  = (const int*)d_in[6];
  float* out = (float*)d_out;

  float* W = (float*)d_ws;
  float* z     = W + Z_OFF;
  int*   cnt   = (int*)(W + CNT_OFF);
  float* ent_s = W + ENTS_OFF;
  int*   idx_s = (int*)(W + IDXS_OFF);
  float* wn    = W + WN_OFF;
  float* zpart = W + ZP_OFF;
  float* ppart = W + PP_OFF;

  // 1: zero the class counters (4 KB)
  hipMemsetAsync(cnt, 0, 1024 * sizeof(int), stream);
  // 2: z-GEMM split-K partials (512 blocks) + old-row scatter (196 blocks)
  fused_scatter_gemm_ab<<<512 + (NN + 255) / 256, 256, 0, stream>>>(
      x, Wf, zpart, labels_idx, ent_in, cnt, ent_s, idx_s);
  // 3: z = sum of partials
  reduce_part<SK1><<<(BB * DD / 4 + 255) / 256, 256, 0, stream>>>(
      zpart, z, BB * DD / 4);
  // 4: p partials = z @ Wc^T (512 blocks)
  gemm_abt_part<<<dim3((CC + 63) / 64, BB / 64, SKP), 256, 0, stream>>>(
      z, Wc, ppart);
  // 5: bias + reduce + argmax + entropy + new-row scatter
  rowstats<<<BB, 256, 0, stream>>>(ppart, bc, cnt, ent_s, idx_s);
  // 6: per-class selection + normalized accumulation + column norm
  class_weights<<<CC, 256, 0, stream>>>(supports_in, z, ent_s, idx_s, cnt, wn);
  // 7: out = z @ wn^T (direct full-K, writes d_out)
  gemm_out<<<dim3((CC + 63) / 64, BB / 32), 256, 0, stream>>>(z, wn, out);
}

// Round 7
// 221.772 us; speedup vs baseline: 1.0295x; 1.0295x over previous
//
#include <hip/hip_runtime.h>
#include <hip/hip_bf16.h>
#include <math.h>

// Problem constants (fixed by setup_inputs)
#define BB   256
#define DIN  2048
#define DD   512
#define CC   1000
#define NN   50000
#define MM   (NN + BB)     // 50256
#define FILTER_K 100
#define SLOT 512           // per-class capacity; max real ~90 old + <=256 new
#define CSTRIDE 16         // one counter per 64B cacheline (atomic contention)

#define SK1  16            // split-K for z = x@Wf  (klen 128)
#define SKP  4             // split-K for p = z@Wc^T (klen 128)

// ---------------- workspace layout (float elements) ----------------
#define Z_OFF     0                          // z:     [256][512]
#define CNT_OFF   (Z_OFF + BB*DD)            // cnt:   [1024*16] int (strided)
#define EI_OFF    (CNT_OFF + 1024*CSTRIDE)   // ei:    [1000][512] float2 (ent,idx)
#define WN_OFF    (EI_OFF + CC*SLOT*2)       // wn:    [1000][512]
#define ZP_OFF    (WN_OFF + CC*DD)           // zpart: [16][256][512]
#define PP_OFF    (ZP_OFF + SK1*BB*DD)       // ppart: [4][256][1000]
// total ~4.9M floats ~20 MB (< 400 MB ws)

// ==== Node 2 (fused): blocks 0..255 -> zpart = x@Wf slice; ====
// ==== blocks 256..451 -> old-row scatter into class slots.  ====
// GEMM: 64x128 tile, 4x8 micro, BK=16, klen=128.
__global__ __launch_bounds__(256, 2) void fused_scatter_gemm_ab(
    const float* __restrict__ A, const float* __restrict__ B,
    float* __restrict__ Cp,
    const int* __restrict__ labels_idx, const float* __restrict__ ent_in,
    int* __restrict__ cnt, float2* __restrict__ ei) {
  __shared__ float As[16][68];
  __shared__ float Bs[16][132];
  const int gbid = blockIdx.x, tid = threadIdx.x;
  if (gbid >= 256) {   // ---- scatter branch ----
    int m = (gbid - 256) * 256 + tid;
    if (m < NN) {
      int c = labels_idx[m];
      int pos = atomicAdd(&cnt[c * CSTRIDE], 1);
      if (pos < SLOT) {
        float2 pr; pr.x = ent_in[m]; pr.y = __int_as_float(m);
        ei[(size_t)c * SLOT + pos] = pr;
      }
    }
    return;
  }
  // ---- GEMM branch ----
  const int m0 = ((gbid >> 2) & 3) * 64;
  const int n0 = (gbid & 3) * 128;
  const int k0 = (gbid >> 4) * 128;
  const int ar = tid >> 2, ac = (tid & 3) * 4;   // A: 64 rows x 16 k
  const int br = tid >> 4, bcn = (tid & 15) * 8; // B: 16 k x 128 n
  const int tm = (tid >> 4) * 4, tn = (tid & 15) * 4;
  float acc[4][8] = {};
  float4 av  = *(const float4*)&A[(size_t)(m0 + ar) * DIN + k0 + ac];
  float4 bv0 = *(const float4*)&B[(size_t)(k0 + br) * DD + n0 + bcn];
  float4 bv1 = *(const float4*)&B[(size_t)(k0 + br) * DD + n0 + bcn + 4];
  for (int kk = 0; kk < 128; kk += 16) {
    __syncthreads();
    As[ac + 0][ar] = av.x; As[ac + 1][ar] = av.y;
    As[ac + 2][ar] = av.z; As[ac + 3][ar] = av.w;
    *(float4*)&Bs[br][bcn] = bv0;
    *(float4*)&Bs[br][bcn + 4] = bv1;
    __syncthreads();
    if (kk + 16 < 128) {   // register prefetch of next K-tile
      av  = *(const float4*)&A[(size_t)(m0 + ar) * DIN + k0 + kk + 16 + ac];
      bv0 = *(const float4*)&B[(size_t)(k0 + kk + 16 + br) * DD + n0 + bcn];
      bv1 = *(const float4*)&B[(size_t)(k0 + kk + 16 + br) * DD + n0 + bcn + 4];
    }
#pragma unroll
    for (int q = 0; q < 16; ++q) {
      float4 a  = *(const float4*)&As[q][tm];
      float4 b0 = *(const float4*)&Bs[q][tn];
      float4 b1 = *(const float4*)&Bs[q][tn + 64];
      float aa[4] = {a.x, a.y, a.z, a.w};
      float bb[8] = {b0.x, b0.y, b0.z, b0.w, b1.x, b1.y, b1.z, b1.w};
#pragma unroll
      for (int i = 0; i < 4; ++i)
#pragma unroll
        for (int j = 0; j < 8; ++j) acc[i][j] += aa[i] * bb[j];
    }
  }
  float* Cb = Cp + (size_t)(gbid >> 4) * BB * DD;
#pragma unroll
  for (int i = 0; i < 4; ++i) {
    *(float4*)&Cb[(size_t)(m0 + tm + i) * DD + n0 + tn] =
        make_float4(acc[i][0], acc[i][1], acc[i][2], acc[i][3]);
    *(float4*)&Cb[(size_t)(m0 + tm + i) * DD + n0 + 64 + tn] =
        make_float4(acc[i][4], acc[i][5], acc[i][6], acc[i][7]);
  }
}

// ============ Node 3: z = sum of 16 split-K partials ================
template <int S>
__global__ __launch_bounds__(256) void reduce_part(
    const float* __restrict__ part, float* __restrict__ out, int n4) {
  int i = blockIdx.x * 256 + threadIdx.x;
  if (i >= n4) return;
  const float4* p4 = (const float4*)part;
  float4 a = p4[i];
#pragma unroll
  for (int s = 1; s < S; ++s) {
    float4 b = p4[(size_t)s * n4 + i];
    a.x += b.x; a.y += b.y; a.z += b.z; a.w += b.w;
  }
  ((float4*)out)[i] = a;
}

// ==== Node 4: ppart[s] = z @ Wc^T  64x64 tile, 4x4 micro, klen=128 ====
__global__ __launch_bounds__(256, 2) void gemm_abt_part(
    const float* __restrict__ A, const float* __restrict__ Bm,
    float* __restrict__ Cp) {
  __shared__ float As[16][68];
  __shared__ float Bs[16][68];
  const int tid = threadIdx.x;
  const int m0 = blockIdx.y * 64;
  const int n0 = blockIdx.x * 64;
  const int k0 = blockIdx.z * 128;
  const int ar = tid >> 2, ac = (tid & 3) * 4;   // 64 rows x 16 k
  const int tm = (tid >> 4) * 4, tn = (tid & 15) * 4;
  float acc[4][4] = {};
  float4 av = *(const float4*)&A[(size_t)(m0 + ar) * DD + k0 + ac];
  float4 bv = make_float4(0.f, 0.f, 0.f, 0.f);
  if (n0 + ar < CC) bv = *(const float4*)&Bm[(size_t)(n0 + ar) * DD + k0 + ac];
  for (int kk = 0; kk < 128; kk += 16) {
    __syncthreads();
    As[ac + 0][ar] = av.x; As[ac + 1][ar] = av.y;
    As[ac + 2][ar] = av.z; As[ac + 3][ar] = av.w;
    Bs[ac + 0][ar] = bv.x; Bs[ac + 1][ar] = bv.y;
    Bs[ac + 2][ar] = bv.z; Bs[ac + 3][ar] = bv.w;
    __syncthreads();
    if (kk + 16 < 128) {   // register prefetch
      av = *(const float4*)&A[(size_t)(m0 + ar) * DD + k0 + kk + 16 + ac];
      if (n0 + ar < CC)
        bv = *(const float4*)&Bm[(size_t)(n0 + ar) * DD + k0 + kk + 16 + ac];
    }
#pragma unroll
    for (int q = 0; q < 16; ++q) {
      float4 a = *(const float4*)&As[q][tm];
      float4 b = *(const float4*)&Bs[q][tn];
      float aa[4] = {a.x, a.y, a.z, a.w};
      float bb[4] = {b.x, b.y, b.z, b.w};
#pragma unroll
      for (int i = 0; i < 4; ++i)
#pragma unroll
        for (int j = 0; j < 4; ++j) acc[i][j] += aa[i] * bb[j];
    }
  }
  float* Cb = Cp + (size_t)blockIdx.z * BB * CC;
#pragma unroll
  for (int i = 0; i < 4; ++i) {
    int n = n0 + tn;
    if (n + 3 < CC) {
      *(float4*)&Cb[(size_t)(m0 + tm + i) * CC + n] =
          make_float4(acc[i][0], acc[i][1], acc[i][2], acc[i][3]);
    } else {
#pragma unroll
      for (int j = 0; j < 4; ++j)
        if (n + j < CC) Cb[(size_t)(m0 + tm + i) * CC + n + j] = acc[i][j];
    }
  }
}

// == Node 5: per-row argmax + entropy over p-partials + bias; scatters NEW row ==
__global__ __launch_bounds__(256) void rowstats(
    const float* __restrict__ ppart, const float* __restrict__ bc,
    int* __restrict__ cnt, float2* __restrict__ ei) {
  const int b = blockIdx.x, tid = threadIdx.x;
  const int lane = tid & 63, wid = tid >> 6;
  float r[4];
  float mv = -INFINITY; int mi = 0x7fffffff;
#pragma unroll
  for (int i = 0; i < 4; ++i) {
    int c = tid + 256 * i;
    if (c < CC) {
      float v = bc[c];
#pragma unroll
      for (int s = 0; s < SKP; ++s)
        v += ppart[(size_t)s * BB * CC + (size_t)b * CC + c];
      r[i] = v;
    } else r[i] = -INFINITY;
    if (r[i] > mv) { mv = r[i]; mi = c; }   // ascending c keeps first max
  }
#pragma unroll
  for (int o = 32; o > 0; o >>= 1) {
    float ov = __shfl_down(mv, o, 64);
    int oi = __shfl_down(mi, o, 64);
    if (ov > mv || (ov == mv && oi < mi)) { mv = ov; mi = oi; }
  }
  __shared__ float smv[4]; __shared__ int smi[4];
  __shared__ float ssm[4], tsm[4];
  if (lane == 0) { smv[wid] = mv; smi[wid] = mi; }
  __syncthreads();
  if (tid == 0) {
#pragma unroll
    for (int w = 1; w < 4; ++w)
      if (smv[w] > smv[0] || (smv[w] == smv[0] && smi[w] < smi[0])) {
        smv[0] = smv[w]; smi[0] = smi[w];
      }
  }
  __syncthreads();
  const float m = smv[0]; const int am = smi[0];
  float s = 0.f, t = 0.f;
#pragma unroll
  for (int i = 0; i < 4; ++i) {
    if (tid + 256 * i < CC) {
      float u = r[i] - m;
      float e = expf(u);
      s += e; t += u * e;
    }
  }
#pragma unroll
  for (int o = 32; o > 0; o >>= 1) {
    s += __shfl_down(s, o, 64);
    t += __shfl_down(t, o, 64);
  }
  if (lane == 0) { ssm[wid] = s; tsm[wid] = t; }
  __syncthreads();
  if (tid == 0) {   // scatter this block's NEW row (original index NN+b)
    float S = ssm[0] + ssm[1] + ssm[2] + ssm[3];
    float T = tsm[0] + tsm[1] + tsm[2] + tsm[3];
    float ent = logf(S) - T / S;
    int pos = atomicAdd(&cnt[am * CSTRIDE], 1);
    if (pos < SLOT) {
      float2 pr; pr.x = ent; pr.y = __int_as_float(NN + b);
      ei[(size_t)am * SLOT + pos] = pr;
    }
  }
}

// == Node 6: per-class select-K, sum normalized rows, column norm ==
// ILP-4 streaming: 4 rows in flight per wave, 4 interleaved shfl chains.
__global__ __launch_bounds__(256) void class_weights(
    const float* __restrict__ supports_in, const float* __restrict__ z,
    const float2* __restrict__ ei, const int* __restrict__ cnt,
    float* __restrict__ wn) {
  const int c = blockIdx.x, tid = threadIdx.x;
  const int lane = tid & 63, wid = tid >> 6;
  int n = cnt[c * CSTRIDE]; if (n > SLOT) n = SLOT;

  __shared__ int sel[SLOT];
  __shared__ float se[SLOT];
  __shared__ int si[SLOT];
  int seln;
  if (n <= FILTER_K) {
    seln = n;
    for (int i = tid; i < n; i += 256)
      sel[i] = __float_as_int(ei[(size_t)c * SLOT + i].y);
  } else {
    for (int i = tid; i < SLOT; i += 256) {
      if (i < n) {
        float2 pr = ei[(size_t)c * SLOT + i];
        se[i] = pr.x; si[i] = __float_as_int(pr.y);
      } else { se[i] = INFINITY; si[i] = 0x7fffffff; }
    }
    __syncthreads();
    for (int k = 2; k <= SLOT; k <<= 1)
      for (int j = k >> 1; j > 0; j >>= 1) {
        for (int i = tid; i < SLOT; i += 256) {
          int ixj = i ^ j;
          if (ixj > i) {
            bool up = ((i & k) == 0);
            float e1 = se[i], e2 = se[ixj];
            int i1 = si[i], i2 = si[ixj];
            bool gt = (e1 > e2) || (e1 == e2 && i1 > i2);
            if (gt == up) { se[i] = e2; se[ixj] = e1; si[i] = i2; si[ixj] = i1; }
          }
        }
        __syncthreads();
      }
    seln = FILTER_K;
    for (int i = tid; i < FILTER_K; i += 256) sel[i] = si[i];
  }
  __syncthreads();
  // pad sel to a multiple of 16 with a valid index; padded rows get scale 0
  const int seln_pad = (seln + 15) & ~15;
  if (seln > 0)
    for (int i = seln + tid; i < seln_pad; i += 256) sel[i] = sel[0];
  __syncthreads();

  // lane owns dims [lane*8, lane*8+8); wave handles 4 rows per iteration
  float4 a0 = make_float4(0.f, 0.f, 0.f, 0.f), a1 = a0;
  for (int t = wid * 4; t < seln_pad; t += 16) {
    float4 u0[4], u1[4]; float s[4];
#pragma unroll
    for (int j = 0; j < 4; ++j) {
      int r = sel[t + j];
      const float4* p4 = (const float4*)((r < NN)
          ? supports_in + (size_t)r * DD : z + (size_t)(r - NN) * DD);
      u0[j] = p4[lane * 2]; u1[j] = p4[lane * 2 + 1];
    }
#pragma unroll
    for (int j = 0; j < 4; ++j)
      s[j] = u0[j].x * u0[j].x + u0[j].y * u0[j].y + u0[j].z * u0[j].z
           + u0[j].w * u0[j].w + u1[j].x * u1[j].x + u1[j].y * u1[j].y
           + u1[j].z * u1[j].z + u1[j].w * u1[j].w;
#pragma unroll
    for (int o = 1; o < 64; o <<= 1) {
#pragma unroll
      for (int j = 0; j < 4; ++j) s[j] += __shfl_xor(s[j], o, 64);
    }
#pragma unroll
    for (int j = 0; j < 4; ++j) {
      float sc = (t + j < seln) ? 1.0f / fmaxf(sqrtf(s[j]), 1e-12f) : 0.f;
      a0.x += u0[j].x * sc; a0.y += u0[j].y * sc;
      a0.z += u0[j].z * sc; a0.w += u0[j].w * sc;
      a1.x += u1[j].x * sc; a1.y += u1[j].y * sc;
      a1.z += u1[j].z * sc; a1.w += u1[j].w * sc;
    }
  }

  __shared__ float part[4][DD];
  *(float4*)&part[wid][lane * 8] = a0;
  *(float4*)&part[wid][lane * 8 + 4] = a1;
  __syncthreads();
  const int d = tid * 2;
  float wx = part[0][d] + part[1][d] + part[2][d] + part[3][d];
  float wy = part[0][d + 1] + part[1][d + 1] + part[2][d + 1] + part[3][d + 1];
  float ss = wx * wx + wy * wy;
#pragma unroll
  for (int o = 1; o < 64; o <<= 1) ss += __shfl_xor(ss, o, 64);
  __shared__ float tot[4];
  if (lane == 0) tot[wid] = ss;
  __syncthreads();
  float S = tot[0] + tot[1] + tot[2] + tot[3];
  float sc = 1.0f / fmaxf(sqrtf(S), 1e-12f);
  ((float2*)(wn + (size_t)c * DD))[tid] = make_float2(wx * sc, wy * sc);
}

// ==== Node 7: out = z @ wn^T, full K=512, 32x64 tile, 2x4 micro ====
__global__ __launch_bounds__(256, 2) void gemm_out(
    const float* __restrict__ A, const float* __restrict__ Bm,
    float* __restrict__ C) {
  __shared__ float As[16][36];
  __shared__ float Bs[16][68];
  const int tid = threadIdx.x;
  const int m0 = blockIdx.y * 32;
  const int n0 = blockIdx.x * 64;
  const int ar = tid >> 3, ac = (tid & 7) * 2;   // A: 32 rows x 16 k (float2)
  const int br = tid >> 2, bc = (tid & 3) * 4;   // B: 64 rows x 16 k (float4)
  const int tm = (tid >> 4) * 2, tn = (tid & 15) * 4;
  float acc[2][4] = {};
  float2 av = *(const float2*)&A[(size_t)(m0 + ar) * DD + ac];
  float4 bv = make_float4(0.f, 0.f, 0.f, 0.f);
  if (n0 + br < CC) bv = *(const float4*)&Bm[(size_t)(n0 + br) * DD + bc];
  for (int k0 = 0; k0 < DD; k0 += 16) {
    __syncthreads();
    As[ac + 0][ar] = av.x; As[ac + 1][ar] = av.y;
    Bs[bc + 0][br] = bv.x; Bs[bc + 1][br] = bv.y;
    Bs[bc + 2][br] = bv.z; Bs[bc + 3][br] = bv.w;
    __syncthreads();
    if (k0 + 16 < DD) {   // register prefetch
      av = *(const float2*)&A[(size_t)(m0 + ar) * DD + k0 + 16 + ac];
      if (n0 + br < CC)
        bv = *(const float4*)&Bm[(size_t)(n0 + br) * DD + k0 + 16 + bc];
    }
#pragma unroll
    for (int q = 0; q < 16; ++q) {
      float2 a = *(const float2*)&As[q][tm];
      float4 b = *(const float4*)&Bs[q][tn];
      float aa[2] = {a.x, a.y};
      float bb[4] = {b.x, b.y, b.z, b.w};
#pragma unroll
      for (int i = 0; i < 2; ++i)
#pragma unroll
        for (int j = 0; j < 4; ++j) acc[i][j] += aa[i] * bb[j];
    }
  }
#pragma unroll
  for (int i = 0; i < 2; ++i) {
    int n = n0 + tn;
    if (n + 3 < CC) {
      *(float4*)&C[(size_t)(m0 + tm + i) * CC + n] =
          make_float4(acc[i][0], acc[i][1], acc[i][2], acc[i][3]);
    } else {
#pragma unroll
      for (int j = 0; j < 4; ++j)
        if (n + j < CC) C[(size_t)(m0 + tm + i) * CC + n + j] = acc[i][j];
    }
  }
}

// ============================ launcher ===================================
extern "C" void kernel_launch(void* const* d_in, const int* in_sizes, int n_in,
                              void* d_out, int out_size, void* d_ws, size_t ws_size,
                              hipStream_t stream) {
  (void)in_sizes; (void)n_in; (void)out_size; (void)ws_size;
  const float* x           = (const float*)d_in[0];
  const float* Wf          = (const float*)d_in[1];
  const float* Wc          = (const float*)d_in[2];
  const float* bc          = (const float*)d_in[3];
  const float* supports_in = (const float*)d_in[4];
  const float* ent_in      = (const float*)d_in[5];
  const int*   labels_idx  = (const int*)d_in[6];
  float* out = (float*)d_out;

  float* W = (float*)d_ws;
  float*  z     = W + Z_OFF;
  int*    cnt   = (int*)(W + CNT_OFF);
  float2* ei    = (float2*)(W + EI_OFF);
  float*  wn    = W + WN_OFF;
  float*  zpart = W + ZP_OFF;
  float*  ppart = W + PP_OFF;

  // 1: zero the strided class counters (64 KB)
  hipMemsetAsync(cnt, 0, 1024 * CSTRIDE * sizeof(int), stream);
  // 2: z-GEMM split-K partials (256 blocks) + old-row scatter (196 blocks)
  fused_scatter_gemm_ab<<<256 + (NN + 255) / 256, 256, 0, stream>>>(
      x, Wf, zpart, labels_idx, ent_in, cnt, ei);
  // 3: z = sum of partials
  reduce_part<SK1><<<(BB * DD / 4 + 255) / 256, 256, 0, stream>>>(
      zpart, z, BB * DD / 4);
  // 4: p partials = z @ Wc^T (256 blocks)
  gemm_abt_part<<<dim3((CC + 63) / 64, BB / 64, SKP), 256, 0, stream>>>(
      z, Wc, ppart);
  // 5: bias + reduce + argmax + entropy + new-row scatter
  rowstats<<<BB, 256, 0, stream>>>(ppart, bc, cnt, ei);
  // 6: per-class selection + normalized accumulation + column norm
  class_weights<<<CC, 256, 0, stream>>>(supports_in, z, ei, cnt, wn);
  // 7: out = z @ wn^T (direct full-K, writes d_out)
  gemm_out<<<dim3((CC + 63) / 64, BB / 32), 256, 0, stream>>>(z, wn, out);
}

// Round 8
// 221.006 us; speedup vs baseline: 1.0331x; 1.0035x over previous
//
#include <hip/hip_runtime.h>
#include <hip/hip_bf16.h>
#include <math.h>

// Problem constants (fixed by setup_inputs)
#define BB   256
#define DIN  2048
#define DD   512
#define CC   1000
#define NN   50000
#define MM   (NN + BB)     // 50256
#define FILTER_K 100
#define SLOT 512           // per-class capacity; max real ~90 old + <=256 new
#define CSTRIDE 16         // one counter per 64B cacheline (atomic contention)

#define SK1  32            // split-K for z = x@Wf  (klen 64)
#define SKP  8             // split-K for p = z@Wc^T (klen 64)

// ---------------- workspace layout (float elements) ----------------
#define Z_OFF     0                          // z:     [256][512]
#define CNT_OFF   (Z_OFF + BB*DD)            // cnt:   [1024*16] int (strided)
#define EI_OFF    (CNT_OFF + 1024*CSTRIDE)   // ei:    [1000][512] float2 (ent,idx)
#define WN_OFF    (EI_OFF + CC*SLOT*2)       // wn:    [1000][512]
#define ZP_OFF    (WN_OFF + CC*DD)           // zpart: [32][256][512]
#define PP_OFF    (ZP_OFF + SK1*BB*DD)       // ppart: [8][256][1000]
// total ~8.0M floats ~32 MB (< 400 MB ws)

// ==== Node 2 (fused): blocks 0..511 -> zpart = x@Wf slice; ====
// ==== blocks 512..707 -> old-row scatter into class slots.  ====
// GEMM: 64x128 tile, 4x8 micro, BK=16, klen=64. 708 blocks (~2.8/CU).
__global__ __launch_bounds__(256, 2) void fused_scatter_gemm_ab(
    const float* __restrict__ A, const float* __restrict__ B,
    float* __restrict__ Cp,
    const int* __restrict__ labels_idx, const float* __restrict__ ent_in,
    int* __restrict__ cnt, float2* __restrict__ ei) {
  __shared__ float As[16][68];
  __shared__ float Bs[16][132];
  const int gbid = blockIdx.x, tid = threadIdx.x;
  if (gbid >= 512) {   // ---- scatter branch ----
    int m = (gbid - 512) * 256 + tid;
    if (m < NN) {
      int c = labels_idx[m];
      int pos = atomicAdd(&cnt[c * CSTRIDE], 1);
      if (pos < SLOT) {
        float2 pr; pr.x = ent_in[m]; pr.y = __int_as_float(m);
        ei[(size_t)c * SLOT + pos] = pr;
      }
    }
    return;
  }
  // ---- GEMM branch ----
  const int m0 = ((gbid >> 2) & 3) * 64;
  const int n0 = (gbid & 3) * 128;
  const int k0 = (gbid >> 4) * 64;
  const int ar = tid >> 2, ac = (tid & 3) * 4;   // A: 64 rows x 16 k
  const int br = tid >> 4, bcn = (tid & 15) * 8; // B: 16 k x 128 n
  const int tm = (tid >> 4) * 4, tn = (tid & 15) * 4;
  float acc[4][8] = {};
  float4 av  = *(const float4*)&A[(size_t)(m0 + ar) * DIN + k0 + ac];
  float4 bv0 = *(const float4*)&B[(size_t)(k0 + br) * DD + n0 + bcn];
  float4 bv1 = *(const float4*)&B[(size_t)(k0 + br) * DD + n0 + bcn + 4];
  for (int kk = 0; kk < 64; kk += 16) {
    __syncthreads();
    As[ac + 0][ar] = av.x; As[ac + 1][ar] = av.y;
    As[ac + 2][ar] = av.z; As[ac + 3][ar] = av.w;
    *(float4*)&Bs[br][bcn] = bv0;
    *(float4*)&Bs[br][bcn + 4] = bv1;
    __syncthreads();
    if (kk + 16 < 64) {   // register prefetch of next K-tile
      av  = *(const float4*)&A[(size_t)(m0 + ar) * DIN + k0 + kk + 16 + ac];
      bv0 = *(const float4*)&B[(size_t)(k0 + kk + 16 + br) * DD + n0 + bcn];
      bv1 = *(const float4*)&B[(size_t)(k0 + kk + 16 + br) * DD + n0 + bcn + 4];
    }
#pragma unroll
    for (int q = 0; q < 16; ++q) {
      float4 a  = *(const float4*)&As[q][tm];
      float4 b0 = *(const float4*)&Bs[q][tn];
      float4 b1 = *(const float4*)&Bs[q][tn + 64];
      float aa[4] = {a.x, a.y, a.z, a.w};
      float bb[8] = {b0.x, b0.y, b0.z, b0.w, b1.x, b1.y, b1.z, b1.w};
#pragma unroll
      for (int i = 0; i < 4; ++i)
#pragma unroll
        for (int j = 0; j < 8; ++j) acc[i][j] += aa[i] * bb[j];
    }
  }
  float* Cb = Cp + (size_t)(gbid >> 4) * BB * DD;
#pragma unroll
  for (int i = 0; i < 4; ++i) {
    *(float4*)&Cb[(size_t)(m0 + tm + i) * DD + n0 + tn] =
        make_float4(acc[i][0], acc[i][1], acc[i][2], acc[i][3]);
    *(float4*)&Cb[(size_t)(m0 + tm + i) * DD + n0 + 64 + tn] =
        make_float4(acc[i][4], acc[i][5], acc[i][6], acc[i][7]);
  }
}

// ============ Node 3: z = sum of 32 split-K partials ================
template <int S>
__global__ __launch_bounds__(256) void reduce_part(
    const float* __restrict__ part, float* __restrict__ out, int n4) {
  int i = blockIdx.x * 256 + threadIdx.x;
  if (i >= n4) return;
  const float4* p4 = (const float4*)part;
  float4 a = p4[i];
#pragma unroll
  for (int s = 1; s < S; ++s) {
    float4 b = p4[(size_t)s * n4 + i];
    a.x += b.x; a.y += b.y; a.z += b.z; a.w += b.w;
  }
  ((float4*)out)[i] = a;
}

// ==== Node 4: ppart[s] = z @ Wc^T  64x64 tile, 4x4 micro, klen=64 ====
// grid (16, 4, 8) = 512 blocks (2/CU).
__global__ __launch_bounds__(256, 2) void gemm_abt_part(
    const float* __restrict__ A, const float* __restrict__ Bm,
    float* __restrict__ Cp) {
  __shared__ float As[16][68];
  __shared__ float Bs[16][68];
  const int tid = threadIdx.x;
  const int m0 = blockIdx.y * 64;
  const int n0 = blockIdx.x * 64;
  const int k0 = blockIdx.z * 64;
  const int ar = tid >> 2, ac = (tid & 3) * 4;   // 64 rows x 16 k
  const int tm = (tid >> 4) * 4, tn = (tid & 15) * 4;
  float acc[4][4] = {};
  float4 av = *(const float4*)&A[(size_t)(m0 + ar) * DD + k0 + ac];
  float4 bv = make_float4(0.f, 0.f, 0.f, 0.f);
  if (n0 + ar < CC) bv = *(const float4*)&Bm[(size_t)(n0 + ar) * DD + k0 + ac];
  for (int kk = 0; kk < 64; kk += 16) {
    __syncthreads();
    As[ac + 0][ar] = av.x; As[ac + 1][ar] = av.y;
    As[ac + 2][ar] = av.z; As[ac + 3][ar] = av.w;
    Bs[ac + 0][ar] = bv.x; Bs[ac + 1][ar] = bv.y;
    Bs[ac + 2][ar] = bv.z; Bs[ac + 3][ar] = bv.w;
    __syncthreads();
    if (kk + 16 < 64) {   // register prefetch
      av = *(const float4*)&A[(size_t)(m0 + ar) * DD + k0 + kk + 16 + ac];
      if (n0 + ar < CC)
        bv = *(const float4*)&Bm[(size_t)(n0 + ar) * DD + k0 + kk + 16 + ac];
    }
#pragma unroll
    for (int q = 0; q < 16; ++q) {
      float4 a = *(const float4*)&As[q][tm];
      float4 b = *(const float4*)&Bs[q][tn];
      float aa[4] = {a.x, a.y, a.z, a.w};
      float bb[4] = {b.x, b.y, b.z, b.w};
#pragma unroll
      for (int i = 0; i < 4; ++i)
#pragma unroll
        for (int j = 0; j < 4; ++j) acc[i][j] += aa[i] * bb[j];
    }
  }
  float* Cb = Cp + (size_t)blockIdx.z * BB * CC;
#pragma unroll
  for (int i = 0; i < 4; ++i) {
    int n = n0 + tn;
    if (n + 3 < CC) {
      *(float4*)&Cb[(size_t)(m0 + tm + i) * CC + n] =
          make_float4(acc[i][0], acc[i][1], acc[i][2], acc[i][3]);
    } else {
#pragma unroll
      for (int j = 0; j < 4; ++j)
        if (n + j < CC) Cb[(size_t)(m0 + tm + i) * CC + n + j] = acc[i][j];
    }
  }
}

// == Node 5: per-row argmax + entropy over p-partials + bias; scatters NEW row ==
__global__ __launch_bounds__(256) void rowstats(
    const float* __restrict__ ppart, const float* __restrict__ bc,
    int* __restrict__ cnt, float2* __restrict__ ei) {
  const int b = blockIdx.x, tid = threadIdx.x;
  const int lane = tid & 63, wid = tid >> 6;
  float r[4];
  float mv = -INFINITY; int mi = 0x7fffffff;
#pragma unroll
  for (int i = 0; i < 4; ++i) {
    int c = tid + 256 * i;
    if (c < CC) {
      float v = bc[c];
#pragma unroll
      for (int s = 0; s < SKP; ++s)
        v += ppart[(size_t)s * BB * CC + (size_t)b * CC + c];
      r[i] = v;
    } else r[i] = -INFINITY;
    if (r[i] > mv) { mv = r[i]; mi = c; }   // ascending c keeps first max
  }
#pragma unroll
  for (int o = 32; o > 0; o >>= 1) {
    float ov = __shfl_down(mv, o, 64);
    int oi = __shfl_down(mi, o, 64);
    if (ov > mv || (ov == mv && oi < mi)) { mv = ov; mi = oi; }
  }
  __shared__ float smv[4]; __shared__ int smi[4];
  __shared__ float ssm[4], tsm[4];
  if (lane == 0) { smv[wid] = mv; smi[wid] = mi; }
  __syncthreads();
  if (tid == 0) {
#pragma unroll
    for (int w = 1; w < 4; ++w)
      if (smv[w] > smv[0] || (smv[w] == smv[0] && smi[w] < smi[0])) {
        smv[0] = smv[w]; smi[0] = smi[w];
      }
  }
  __syncthreads();
  const float m = smv[0]; const int am = smi[0];
  float s = 0.f, t = 0.f;
#pragma unroll
  for (int i = 0; i < 4; ++i) {
    if (tid + 256 * i < CC) {
      float u = r[i] - m;
      float e = expf(u);
      s += e; t += u * e;
    }
  }
#pragma unroll
  for (int o = 32; o > 0; o >>= 1) {
    s += __shfl_down(s, o, 64);
    t += __shfl_down(t, o, 64);
  }
  if (lane == 0) { ssm[wid] = s; tsm[wid] = t; }
  __syncthreads();
  if (tid == 0) {   // scatter this block's NEW row (original index NN+b)
    float S = ssm[0] + ssm[1] + ssm[2] + ssm[3];
    float T = tsm[0] + tsm[1] + tsm[2] + tsm[3];
    float ent = logf(S) - T / S;
    int pos = atomicAdd(&cnt[am * CSTRIDE], 1);
    if (pos < SLOT) {
      float2 pr; pr.x = ent; pr.y = __int_as_float(NN + b);
      ei[(size_t)am * SLOT + pos] = pr;
    }
  }
}

// == Node 6: per-class select-K, sum normalized rows, column norm ==
// ILP-4 streaming: 4 rows in flight per wave, 4 interleaved shfl chains.
__global__ __launch_bounds__(256) void class_weights(
    const float* __restrict__ supports_in, const float* __restrict__ z,
    const float2* __restrict__ ei, const int* __restrict__ cnt,
    float* __restrict__ wn) {
  const int c = blockIdx.x, tid = threadIdx.x;
  const int lane = tid & 63, wid = tid >> 6;
  int n = cnt[c * CSTRIDE]; if (n > SLOT) n = SLOT;

  __shared__ int sel[SLOT];
  __shared__ float se[SLOT];
  __shared__ int si[SLOT];
  int seln;
  if (n <= FILTER_K) {
    seln = n;
    for (int i = tid; i < n; i += 256)
      sel[i] = __float_as_int(ei[(size_t)c * SLOT + i].y);
  } else {
    for (int i = tid; i < SLOT; i += 256) {
      if (i < n) {
        float2 pr = ei[(size_t)c * SLOT + i];
        se[i] = pr.x; si[i] = __float_as_int(pr.y);
      } else { se[i] = INFINITY; si[i] = 0x7fffffff; }
    }
    __syncthreads();
    for (int k = 2; k <= SLOT; k <<= 1)
      for (int j = k >> 1; j > 0; j >>= 1) {
        for (int i = tid; i < SLOT; i += 256) {
          int ixj = i ^ j;
          if (ixj > i) {
            bool up = ((i & k) == 0);
            float e1 = se[i], e2 = se[ixj];
            int i1 = si[i], i2 = si[ixj];
            bool gt = (e1 > e2) || (e1 == e2 && i1 > i2);
            if (gt == up) { se[i] = e2; se[ixj] = e1; si[i] = i2; si[ixj] = i1; }
          }
        }
        __syncthreads();
      }
    seln = FILTER_K;
    for (int i = tid; i < FILTER_K; i += 256) sel[i] = si[i];
  }
  __syncthreads();
  // pad sel to a multiple of 16 with a valid index; padded rows get scale 0
  const int seln_pad = (seln + 15) & ~15;
  if (seln > 0)
    for (int i = seln + tid; i < seln_pad; i += 256) sel[i] = sel[0];
  __syncthreads();

  // lane owns dims [lane*8, lane*8+8); wave handles 4 rows per iteration
  float4 a0 = make_float4(0.f, 0.f, 0.f, 0.f), a1 = a0;
  for (int t = wid * 4; t < seln_pad; t += 16) {
    float4 u0[4], u1[4]; float s[4];
#pragma unroll
    for (int j = 0; j < 4; ++j) {
      int r = sel[t + j];
      const float4* p4 = (const float4*)((r < NN)
          ? supports_in + (size_t)r * DD : z + (size_t)(r - NN) * DD);
      u0[j] = p4[lane * 2]; u1[j] = p4[lane * 2 + 1];
    }
#pragma unroll
    for (int j = 0; j < 4; ++j)
      s[j] = u0[j].x * u0[j].x + u0[j].y * u0[j].y + u0[j].z * u0[j].z
           + u0[j].w * u0[j].w + u1[j].x * u1[j].x + u1[j].y * u1[j].y
           + u1[j].z * u1[j].z + u1[j].w * u1[j].w;
#pragma unroll
    for (int o = 1; o < 64; o <<= 1) {
#pragma unroll
      for (int j = 0; j < 4; ++j) s[j] += __shfl_xor(s[j], o, 64);
    }
#pragma unroll
    for (int j = 0; j < 4; ++j) {
      float sc = (t + j < seln) ? 1.0f / fmaxf(sqrtf(s[j]), 1e-12f) : 0.f;
      a0.x += u0[j].x * sc; a0.y += u0[j].y * sc;
      a0.z += u0[j].z * sc; a0.w += u0[j].w * sc;
      a1.x += u1[j].x * sc; a1.y += u1[j].y * sc;
      a1.z += u1[j].z * sc; a1.w += u1[j].w * sc;
    }
  }

  __shared__ float part[4][DD];
  *(float4*)&part[wid][lane * 8] = a0;
  *(float4*)&part[wid][lane * 8 + 4] = a1;
  __syncthreads();
  const int d = tid * 2;
  float wx = part[0][d] + part[1][d] + part[2][d] + part[3][d];
  float wy = part[0][d + 1] + part[1][d + 1] + part[2][d + 1] + part[3][d + 1];
  float ss = wx * wx + wy * wy;
#pragma unroll
  for (int o = 1; o < 64; o <<= 1) ss += __shfl_xor(ss, o, 64);
  __shared__ float tot[4];
  if (lane == 0) tot[wid] = ss;
  __syncthreads();
  float S = tot[0] + tot[1] + tot[2] + tot[3];
  float sc = 1.0f / fmaxf(sqrtf(S), 1e-12f);
  ((float2*)(wn + (size_t)c * DD))[tid] = make_float2(wx * sc, wy * sc);
}

// ==== Node 7: out = z @ wn^T, full K=512, 16x64 tile, 1x4 micro ====
// grid (16 n, 16 m) = 256 blocks (1/CU, all CUs active).
__global__ __launch_bounds__(256, 2) void gemm_out(
    const float* __restrict__ A, const float* __restrict__ Bm,
    float* __restrict__ C) {
  __shared__ float As[16][20];   // [k][row]
  __shared__ float Bs[16][68];   // [k][n]
  const int tid = threadIdx.x;
  const int m0 = blockIdx.y * 16;
  const int n0 = blockIdx.x * 64;
  const int arow = tid >> 4, ak = tid & 15;      // A: 16 rows x 16 k (scalar)
  const int br = tid >> 2, bc = (tid & 3) * 4;   // B: 64 rows x 16 k (float4)
  const int tr = tid >> 4, tn4 = (tid & 15) * 4;
  float acc[4] = {};
  float av = A[(size_t)(m0 + arow) * DD + ak];
  float4 bv = make_float4(0.f, 0.f, 0.f, 0.f);
  if (n0 + br < CC) bv = *(const float4*)&Bm[(size_t)(n0 + br) * DD + bc];
  for (int k0 = 0; k0 < DD; k0 += 16) {
    __syncthreads();
    As[ak][arow] = av;
    Bs[bc + 0][br] = bv.x; Bs[bc + 1][br] = bv.y;
    Bs[bc + 2][br] = bv.z; Bs[bc + 3][br] = bv.w;
    __syncthreads();
    if (k0 + 16 < DD) {   // register prefetch
      av = A[(size_t)(m0 + arow) * DD + k0 + 16 + ak];
      if (n0 + br < CC)
        bv = *(const float4*)&Bm[(size_t)(n0 + br) * DD + k0 + 16 + bc];
    }
#pragma unroll
    for (int q = 0; q < 16; ++q) {
      float a = As[q][tr];
      float4 b = *(const float4*)&Bs[q][tn4];
      acc[0] += a * b.x; acc[1] += a * b.y;
      acc[2] += a * b.z; acc[3] += a * b.w;
    }
  }
  int n = n0 + tn4;
  if (n + 3 < CC) {
    *(float4*)&C[(size_t)(m0 + tr) * CC + n] =
        make_float4(acc[0], acc[1], acc[2], acc[3]);
  } else {
#pragma unroll
    for (int j = 0; j < 4; ++j)
      if (n + j < CC) C[(size_t)(m0 + tr) * CC + n + j] = acc[j];
  }
}

// ============================ launcher ===================================
extern "C" void kernel_launch(void* const* d_in, const int* in_sizes, int n_in,
                              void* d_out, int out_size, void* d_ws, size_t ws_size,
                              hipStream_t stream) {
  (void)in_sizes; (void)n_in; (void)out_size; (void)ws_size;
  const float* x           = (const float*)d_in[0];
  const float* Wf          = (const float*)d_in[1];
  const float* Wc          = (const float*)d_in[2];
  const float* bc          = (const float*)d_in[3];
  const float* supports_in = (const float*)d_in[4];
  const float* ent_in      = (const float*)d_in[5];
  const int*   labels_idx  = (const int*)d_in[6];
  float* out = (float*)d_out;

  float* W = (float*)d_ws;
  float*  z     = W + Z_OFF;
  int*    cnt   = (int*)(W + CNT_OFF);
  float2* ei    = (float2*)(W + EI_OFF);
  float*  wn    = W + WN_OFF;
  float*  zpart = W + ZP_OFF;
  float*  ppart = W + PP_OFF;

  // 1: zero the strided class counters (64 KB)
  hipMemsetAsync(cnt, 0, 1024 * CSTRIDE * sizeof(int), stream);
  // 2: z-GEMM split-K partials (512 blocks) + old-row scatter (196 blocks)
  fused_scatter_gemm_ab<<<512 + (NN + 255) / 256, 256, 0, stream>>>(
      x, Wf, zpart, labels_idx, ent_in, cnt, ei);
  // 3: z = sum of partials
  reduce_part<SK1><<<(BB * DD / 4 + 255) / 256, 256, 0, stream>>>(
      zpart, z, BB * DD / 4);
  // 4: p partials = z @ Wc^T (512 blocks)
  gemm_abt_part<<<dim3((CC + 63) / 64, BB / 64, SKP), 256, 0, stream>>>(
      z, Wc, ppart);
  // 5: bias + reduce + argmax + entropy + new-row scatter
  rowstats<<<BB, 256, 0, stream>>>(ppart, bc, cnt, ei);
  // 6: per-class selection + normalized accumulation + column norm
  class_weights<<<CC, 256, 0, stream>>>(supports_in, z, ei, cnt, wn);
  // 7: out = z @ wn^T (direct full-K, writes d_out, 256 blocks)
  gemm_out<<<dim3((CC + 63) / 64, BB / 16), 256, 0, stream>>>(z, wn, out);
}